// Round 4
// baseline (503.647 us; speedup 1.0000x reference)
//
#include <hip/hip_runtime.h>
#include <hip/hip_bf16.h>
#include <cstdio>

#define TPB 256
#define B_ 4
#define H_ 128
#define W_ 128
#define D_ 768
#define FW 65
#define BH_ 512                  // B_*H_
#define THRESH_ 0.01f
#define NEG_TWO_PI_OVER_128 (-0.04908738521234052f)

typedef short bf16x8 __attribute__((ext_vector_type(8)));
typedef float f32x4 __attribute__((ext_vector_type(4)));

// fq (in d_ws): one u32 per (point, channel) = packed (bf16 re, bf16 im)
//   u32 index = ((b*128 + h)*65 + fw)*768 + d
// Mixed-radix 128 = 4*4*4*2 DIF; slot(k) = digit-reverse:
//   s(k) = ((k&3)<<5) | (((k>>2)&3)<<3) | (((k>>4)&3)<<1) | ((k>>6)&1)

__device__ __forceinline__ unsigned pk(float lo, float hi) {
  __hip_bfloat162 h2 = __float22bfloat162_rn(make_float2(lo, hi));
  return *(unsigned*)&h2;
}
__device__ __forceinline__ float2 upk(unsigned u) {
  return __bfloat1622float2(*(__hip_bfloat162*)&u);
}
__device__ __forceinline__ int drev(int k) {
  return ((k & 3) << 5) | (((k >> 2) & 3) << 3) | (((k >> 4) & 3) << 1) | ((k >> 6) & 1);
}

// radix-4 DIF butterfly, in-place on 4 LDS slots. FWD: e^-i; !FWD: e^+i.
template <bool FWD>
__device__ __forceinline__ void bfly4(float* re, float* im, int i0, int i1, int i2, int i3,
                                      float c1, float s1, float c2, float s2, float c3, float s3) {
  const float x0r = re[i0], x0i = im[i0], x1r = re[i1], x1i = im[i1];
  const float x2r = re[i2], x2i = im[i2], x3r = re[i3], x3i = im[i3];
  const float v0r = x0r + x2r, v0i = x0i + x2i, v2r = x0r - x2r, v2i = x0i - x2i;
  const float v1r = x1r + x3r, v1i = x1i + x3i, v3r = x1r - x3r, v3i = x1i - x3i;
  float u1r, u1i, u3r, u3i;
  if (FWD) { u1r = v2r + v3i; u1i = v2i - v3r; u3r = v2r - v3i; u3i = v2i + v3r; }
  else     { u1r = v2r - v3i; u1i = v2i + v3r; u3r = v2r + v3i; u3i = v2i - v3r; }
  const float u2r = v0r - v1r, u2i = v0i - v1i;
  re[i0] = v0r + v1r; im[i0] = v0i + v1i;
  re[i1] = u1r * c1 - u1i * s1; im[i1] = u1r * s1 + u1i * c1;
  re[i2] = u2r * c2 - u2i * s2; im[i2] = u2r * s2 + u2i * c2;
  re[i3] = u3r * c3 - u3i * s3; im[i3] = u3r * s3 + u3i * c3;
}

// ===================== 256-thread [slot*32+col] helpers (W-axis kernels) ====
template <bool FWD>
__device__ __forceinline__ void run_stage(float* re, float* im, int t,
                                          int npmask, int npbits, int span, int twm,
                                          const float* twr, const float* twi) {
#pragma unroll
  for (int it = 0; it < 4; ++it) {
    const int gid = it * TPB + t;
    const int cc = gid & 31, g = gid >> 5;
    const int np = g & npmask, blk = g >> npbits;
    const int base = blk * (span << 2) + np;
    const int i0 = base * 32 + cc, i1 = (base + span) * 32 + cc;
    const int i2 = (base + 2 * span) * 32 + cc, i3 = (base + 3 * span) * 32 + cc;
    const int tb = np * twm;
    float c1 = twr[tb], s1 = twi[tb];
    float c2 = twr[2 * tb], s2 = twi[2 * tb];
    float c3 = twr[3 * tb], s3 = twi[3 * tb];
    if (!FWD) { s1 = -s1; s2 = -s2; s3 = -s3; }
    bfly4<FWD>(re, im, i0, i1, i2, i3, c1, s1, c2, s2, c3, s3);
  }
  __syncthreads();
}

__device__ __forceinline__ void run_r2(float* re, float* im, int t) {
#pragma unroll
  for (int it = 0; it < 8; ++it) {
    const int pid = it * TPB + t;
    const int cc = pid & 31, p = pid >> 5;
    const int i0 = (2 * p) * 32 + cc, i1 = i0 + 32;
    const float ar = re[i0], ai = im[i0], br = re[i1], bi = im[i1];
    re[i0] = ar + br; im[i0] = ai + bi;
    re[i1] = ar - br; im[i1] = ai - bi;
  }
  __syncthreads();
}

#define TW_INIT() do { if (t < 128) { float s_, c_; \
    __sincosf(NEG_TWO_PI_OVER_128 * (float)t, &s_, &c_); twr[t] = c_; twi[t] = s_; } } while (0)

// ===================== 512-thread swizzled helpers (k_mid) ==================
// f32 index for (slot s, chan c): s*96 + (c ^ ((s&7)<<2))  [XOR of byte bits 4-6]
__device__ __forceinline__ int midx(int s, int c) { return s * 96 + (c ^ ((s & 7) << 2)); }

template <bool FWD>
__device__ __forceinline__ void stage512(float* re, float* im, int t,
                                         int npmask, int npbits, int span, int twm,
                                         const float* twr, const float* twi) {
#pragma unroll
  for (int it = 0; it < 6; ++it) {
    const int gid = it * 512 + t;
    const int c5 = gid & 31;
    const int rest = gid >> 5;            // 0..95
    const int g = rest & 31, cblk = rest >> 5;
    const int col = cblk * 32 + c5;
    const int np = g & npmask, blk = g >> npbits;
    const int base = blk * (span << 2) + np;
    const int i0 = midx(base, col), i1 = midx(base + span, col);
    const int i2 = midx(base + 2 * span, col), i3 = midx(base + 3 * span, col);
    const int tb = np * twm;
    float c1 = twr[tb], s1 = twi[tb];
    float c2 = twr[2 * tb], s2 = twi[2 * tb];
    float c3 = twr[3 * tb], s3 = twi[3 * tb];
    if (!FWD) { s1 = -s1; s2 = -s2; s3 = -s3; }
    bfly4<FWD>(re, im, i0, i1, i2, i3, c1, s1, c2, s2, c3, s3);
  }
  __syncthreads();
}

__device__ __forceinline__ void dit512(float* re, float* im, int t,
                                       int npmask, int npbits, int span, int twm,
                                       const float* twr, const float* twi) {
#pragma unroll
  for (int it = 0; it < 6; ++it) {
    const int gid = it * 512 + t;
    const int c5 = gid & 31;
    const int rest = gid >> 5;
    const int g = rest & 31, cblk = rest >> 5;
    const int col = cblk * 32 + c5;
    const int np = g & npmask, blk = g >> npbits;
    const int base = blk * (span << 2) + np;
    const int i0 = midx(base, col), i1 = midx(base + span, col);
    const int i2 = midx(base + 2 * span, col), i3 = midx(base + 3 * span, col);
    const int tb = np * twm;
    const float c1 = twr[tb], s1 = twi[tb];
    const float c2 = twr[2 * tb], s2 = twi[2 * tb];
    const float c3 = twr[3 * tb], s3 = twi[3 * tb];
    const float t0r = re[i0], t0i = im[i0];
    const float y1r = re[i1], y1i = im[i1], y2r = re[i2], y2i = im[i2], y3r = re[i3], y3i = im[i3];
    const float t1r = y1r * c1 + y1i * s1, t1i = y1i * c1 - y1r * s1;
    const float t2r = y2r * c2 + y2i * s2, t2i = y2i * c2 - y2r * s2;
    const float t3r = y3r * c3 + y3i * s3, t3i = y3i * c3 - y3r * s3;
    const float w0r = t0r + t2r, w0i = t0i + t2i, w2r = t0r - t2r, w2i = t0i - t2i;
    const float w1r = t1r + t3r, w1i = t1i + t3i, w3r = t1r - t3r, w3i = t1i - t3i;
    re[i0] = w0r + w1r; im[i0] = w0i + w1i;
    re[i1] = w2r - w3i; im[i1] = w2i + w3r;
    re[i2] = w0r - w1r; im[i2] = w0i - w1i;
    re[i3] = w2r + w3i; im[i3] = w2i - w3r;
  }
  __syncthreads();
}

__device__ __forceinline__ void r2_512(float* re, float* im, int t) {
#pragma unroll
  for (int it = 0; it < 12; ++it) {
    const int gid = it * 512 + t;
    const int c5 = gid & 31;
    const int rest = gid >> 5;           // 0..191
    const int p = rest & 63, cblk = rest >> 6;
    const int col = cblk * 32 + c5;
    const int i0 = midx(2 * p, col), i1 = midx(2 * p + 1, col);
    const float ar = re[i0], ai = im[i0], br = re[i1], bi = im[i1];
    re[i0] = ar + br; im[i0] = ai + bi;
    re[i1] = ar - br; im[i1] = ai - bi;
  }
  __syncthreads();
}

// ---------------------------------------------------------------------------
// K0: pack complex weights into bf16 B-fragment order (block form Wc).
// ---------------------------------------------------------------------------
__global__ __launch_bounds__(TPB) void k_wpack(const float* __restrict__ w1r,
                                               const float* __restrict__ w1i,
                                               const float* __restrict__ w2r,
                                               const float* __restrict__ w2i,
                                               unsigned short* __restrict__ wp) {
  const int tid = blockIdx.x * TPB + threadIdx.x;
  if (tid >= 2 * 36864) return;
  const int L = tid / 36864, rem = tid % 36864;
  const int n = rem / 192, k = rem % 192;
  const int c = k >> 1, s = k & 1, o = n >> 1, t = n & 1;
  const float* wr = L ? w2r : w1r;
  const float* wi = L ? w2i : w1i;
  const float val = (s == 0) ? (t == 0 ? wr[o * 96 + c] : wi[o * 96 + c])
                             : (t == 0 ? -wi[o * 96 + c] : wr[o * 96 + c]);
  __hip_bfloat16 h = __float2bfloat16(val);
  const int idx = ((n * 6 + (k >> 5)) * 4 + ((k >> 3) & 3)) * 8 + (k & 7);
  wp[L * 36864 + idx] = *(unsigned short*)&h;
}

// ---------------------------------------------------------------------------
// K1: forward rFFT over W via real-pair packing. grid (512, 12). bf16 out.
// ---------------------------------------------------------------------------
__global__ __launch_bounds__(TPB) void k_fwd_w(const float* __restrict__ x,
                                               unsigned* __restrict__ fq) {
  __shared__ float re[4096], im[4096], twr[128], twi[128];
  const int t = threadIdx.x;
  const int bh = blockIdx.x;
  const int d0 = blockIdx.y << 6;
  TW_INIT();
  const float2* xp = (const float2*)(x + (size_t)bh * 98304 + d0);
#pragma unroll
  for (int it = 0; it < 16; ++it) {
    const int w = (it << 3) + (t >> 5), c = t & 31;
    const float2 v = xp[w * 384 + c];
    re[w * 32 + c] = v.x; im[w * 32 + c] = v.y;
  }
  __syncthreads();
  run_stage<true>(re, im, t, 31, 5, 32, 1, twr, twi);
  run_stage<true>(re, im, t, 7, 3, 8, 4, twr, twi);
  run_stage<true>(re, im, t, 1, 1, 2, 16, twr, twi);
  run_r2(re, im, t);
#pragma unroll
  for (int it = 0; it < 9; ++it) {
    const int idx = it * TPB + t;
    if (idx < FW * 32) {
      const int q = idx >> 5, c = idx & 31;
      const int sq = drev(q), sm = drev((128 - q) & 127);
      const float a = re[sq * 32 + c], b = im[sq * 32 + c];
      const float cr = re[sm * 32 + c], dr = -im[sm * 32 + c];
      const float hsc = 0.00390625f;  // 0.5 * (1/128)
      const float xer = (a + cr) * hsc, xei = (b + dr) * hsc;
      const float xor_ = (b - dr) * hsc, xoi = (cr - a) * hsc;
      *(uint2*)(fq + (size_t)(bh * FW + q) * 768 + d0 + 2 * c) =
          make_uint2(pk(xer, xei), pk(xor_, xoi));
    }
  }
}

// ---------------------------------------------------------------------------
// K2 (fused): H-FFT (fwd) -> complex MLP (MFMA) -> H-iFFT, all in LDS.
// grid (8 blk, 65 fw, 4 b), 512 threads. LDS 99 KB f32 re/im, swizzled.
// ---------------------------------------------------------------------------
__global__ __launch_bounds__(512, 1) void k_mid(unsigned* __restrict__ fq,
    const bf16x8* __restrict__ wpb,
    const float* __restrict__ b1, const float* __restrict__ b2) {
  extern __shared__ float sm[];
  float* re  = sm;
  float* im  = sm + 12288;
  float* twr = sm + 24576;
  float* twi = sm + 24704;
  const int t = threadIdx.x;
  const int blk = blockIdx.x, fw = blockIdx.y, b = blockIdx.z;
  TW_INIT();
  unsigned* fp = fq + ((size_t)(b * 128) * FW + fw) * 768 + blk * 96;  // h stride 49920

  // ---- load 128 h x 96 chans, unpack bf16 -> f32 swizzled LDS ----
#pragma unroll
  for (int it = 0; it < 12; ++it) {
    const int gid = it * 512 + t;
    const int uc = gid % 48, h = gid / 48;
    const uint2 v = *(const uint2*)(fp + (size_t)h * (FW * 768) + 2 * uc);
    const float2 e0 = upk(v.x), e1 = upk(v.y);
    const int idx = midx(h, 2 * uc);      // 2*uc even -> idx, idx+1 contiguous
    *(float2*)(re + idx) = make_float2(e0.x, e1.x);
    *(float2*)(im + idx) = make_float2(e0.y, e1.y);
  }
  __syncthreads();

  // ---- forward H-FFT (DIF, digit-reversed slots) ----
  stage512<true>(re, im, t, 31, 5, 32, 1, twr, twi);
  stage512<true>(re, im, t, 7, 3, 8, 4, twr, twi);
  stage512<true>(re, im, t, 1, 1, 2, 16, twr, twi);
  r2_512(re, im, t);

  // ---- MLP: M=128 slots, K=N=192 interleaved re/im features ----
  const int wv = t >> 6, l = t & 63;
  const int c16 = l & 15, g4 = l >> 4;
  const int wr = wv >> 2, wc = wv & 3;
  const int n0 = wc * 48, row0 = wr * 64;

  float bA[3], bB[3];
#pragma unroll
  for (int np = 0; np < 3; ++np) {
    bA[np] = b1[n0 + np * 16 + c16];
    bB[np] = b2[n0 + np * 16 + c16];
  }

  f32x4 acc[4][3];
#pragma unroll
  for (int mt = 0; mt < 4; ++mt)
#pragma unroll
    for (int np = 0; np < 3; ++np) acc[mt][np] = (f32x4)0.f;

  // layer 1
  for (int kk = 0; kk < 6; ++kk) {
    bf16x8 a[4];
#pragma unroll
    for (int mt = 0; mt < 4; ++mt) {
      const int row = row0 + mt * 16 + c16;
      const int idx = midx(row, kk * 16 + g4 * 4);
      const f32x4 r4 = *(const f32x4*)(re + idx);
      const f32x4 i4 = *(const f32x4*)(im + idx);
      unsigned u[4];
#pragma unroll
      for (int j = 0; j < 4; ++j) u[j] = pk(r4[j], i4[j]);
      a[mt] = *(bf16x8*)u;
    }
    bf16x8 bfr[3];
#pragma unroll
    for (int np = 0; np < 3; ++np) bfr[np] = wpb[((n0 + np * 16 + c16) * 6 + kk) * 4 + g4];
#pragma unroll
    for (int mt = 0; mt < 4; ++mt)
#pragma unroll
      for (int np = 0; np < 3; ++np)
        acc[mt][np] = __builtin_amdgcn_mfma_f32_16x16x32_bf16(a[mt], bfr[np], acc[mt][np], 0, 0, 0);
  }
  __syncthreads();  // all layer-1 reads complete

  // bias + ReLU -> hidden (f32, same arrays; col even -> re, odd -> im)
#pragma unroll
  for (int mt = 0; mt < 4; ++mt)
#pragma unroll
    for (int np = 0; np < 3; ++np) {
      const int col = n0 + np * 16 + c16;
      const int ch = col >> 1;
      float* dst = (col & 1) ? im : re;
#pragma unroll
      for (int r = 0; r < 4; ++r) {
        const int row = row0 + mt * 16 + g4 * 4 + r;
        dst[midx(row, ch) + (ch ^ ((row & 7) << 2)) - (ch ^ ((row & 7) << 2))] =
            fmaxf(acc[mt][np][r] + bA[np], 0.f);
      }
    }
  __syncthreads();  // hidden visible

  // layer 2
#pragma unroll
  for (int mt = 0; mt < 4; ++mt)
#pragma unroll
    for (int np = 0; np < 3; ++np) acc[mt][np] = (f32x4)0.f;
  const bf16x8* wpb2 = wpb + 4608;
  for (int kk = 0; kk < 6; ++kk) {
    bf16x8 a[4];
#pragma unroll
    for (int mt = 0; mt < 4; ++mt) {
      const int row = row0 + mt * 16 + c16;
      const int idx = midx(row, kk * 16 + g4 * 4);
      const f32x4 r4 = *(const f32x4*)(re + idx);
      const f32x4 i4 = *(const f32x4*)(im + idx);
      unsigned u[4];
#pragma unroll
      for (int j = 0; j < 4; ++j) u[j] = pk(r4[j], i4[j]);
      a[mt] = *(bf16x8*)u;
    }
    bf16x8 bfr[3];
#pragma unroll
    for (int np = 0; np < 3; ++np) bfr[np] = wpb2[((n0 + np * 16 + c16) * 6 + kk) * 4 + g4];
#pragma unroll
    for (int mt = 0; mt < 4; ++mt)
#pragma unroll
      for (int np = 0; np < 3; ++np)
        acc[mt][np] = __builtin_amdgcn_mfma_f32_16x16x32_bf16(a[mt], bfr[np], acc[mt][np], 0, 0, 0);
  }
  __syncthreads();  // all layer-2 reads complete

  // bias + softshrink -> back to re/im (f32)
#pragma unroll
  for (int mt = 0; mt < 4; ++mt)
#pragma unroll
    for (int np = 0; np < 3; ++np) {
      const int col = n0 + np * 16 + c16;
      const int ch = col >> 1;
      float* dst = (col & 1) ? im : re;
#pragma unroll
      for (int r = 0; r < 4; ++r) {
        const int row = row0 + mt * 16 + g4 * 4 + r;
        float vv = acc[mt][np][r] + bB[np];
        vv = (vv > THRESH_) ? (vv - THRESH_) : ((vv < -THRESH_) ? (vv + THRESH_) : 0.f);
        dst[midx(row, ch)] = vv;
      }
    }
  __syncthreads();

  // ---- inverse H-FFT (DIT: digit-reversed in, natural out, e^+i) ----
  r2_512(re, im, t);
  dit512(re, im, t, 1, 1, 2, 16, twr, twi);
  dit512(re, im, t, 7, 3, 8, 4, twr, twi);
  dit512(re, im, t, 31, 5, 32, 1, twr, twi);

  // ---- pack bf16 and store ----
#pragma unroll
  for (int it = 0; it < 12; ++it) {
    const int gid = it * 512 + t;
    const int uc = gid % 48, h = gid / 48;
    const int idx = midx(h, 2 * uc);
    const float2 r2v = *(const float2*)(re + idx);
    const float2 i2v = *(const float2*)(im + idx);
    *(uint2*)(fp + (size_t)h * (FW * 768) + 2 * uc) =
        make_uint2(pk(r2v.x, i2v.x), pk(r2v.y, i2v.y));
  }
}

// ---------------------------------------------------------------------------
// K3: inverse rFFT over W via pair packing + skip-add. grid (512, 12).
// ---------------------------------------------------------------------------
__global__ __launch_bounds__(TPB) void k_inv_w(const unsigned* __restrict__ fq,
                                               const float* __restrict__ x,
                                               float* __restrict__ out) {
  __shared__ float re[4096], im[4096], twr[128], twi[128];
  const int t = threadIdx.x;
  const int bh = blockIdx.x;
  const int d0 = blockIdx.y << 6;
  TW_INIT();
#pragma unroll
  for (int it = 0; it < 9; ++it) {
    const int idx = it * TPB + t;
    if (idx < FW * 32) {
      const int q = idx >> 5, c = idx & 31;
      const uint2 vv = *(const uint2*)(fq + (size_t)(bh * FW + q) * 768 + d0 + 2 * c);
      const float2 e = upk(vv.x), o = upk(vv.y);
      re[q * 32 + c] = e.x - o.y; im[q * 32 + c] = e.y + o.x;
      if (q >= 1 && q <= 63) {
        re[(128 - q) * 32 + c] = e.x + o.y;
        im[(128 - q) * 32 + c] = o.x - e.y;
      }
    }
  }
  __syncthreads();
  run_stage<false>(re, im, t, 31, 5, 32, 1, twr, twi);
  run_stage<false>(re, im, t, 7, 3, 8, 4, twr, twi);
  run_stage<false>(re, im, t, 1, 1, 2, 16, twr, twi);
  run_r2(re, im, t);
  const float sc = 0.0078125f;  // 1/128
#pragma unroll
  for (int it = 0; it < 16; ++it) {
    const int w = (it << 3) + (t >> 5), c = t & 31;
    const int s = drev(w);
    const float yr = re[s * 32 + c] * sc, yi = im[s * 32 + c] * sc;
    const size_t fi = (size_t)bh * 49152 + w * 384 + (d0 >> 1) + c;
    const float2 xv = ((const float2*)x)[fi];
    ((float2*)out)[fi] = make_float2(yr + xv.x, yi + xv.y);
  }
}

// ---------------------------------------------------------------------------
extern "C" void kernel_launch(void* const* d_in, const int* in_sizes, int n_in,
                              void* d_out, int out_size, void* d_ws, size_t ws_size,
                              hipStream_t stream) {
  const float* x   = (const float*)d_in[0];
  const float* w1r = (const float*)d_in[1];
  const float* w1i = (const float*)d_in[2];
  const float* b1  = (const float*)d_in[3];
  const float* w2r = (const float*)d_in[4];
  const float* w2i = (const float*)d_in[5];
  const float* b2  = (const float*)d_in[6];
  unsigned* fq = (unsigned*)d_ws;
  float* out = (float*)d_out;

  const size_t need = (size_t)BH_ * FW * 768 * 4;  // 102,236,160 B
  if (ws_size < need) {
    fprintf(stderr, "kernel_launch: ws too small (%zu < %zu)\n", ws_size, need);
    return;
  }

  // packed bf16 weights at start of d_out (fully overwritten by k_inv_w later)
  unsigned short* wp = (unsigned short*)d_out;

  const int MID_SMEM = (24576 + 256) * 4;  // 99,328 B
  hipFuncSetAttribute((const void*)k_mid, hipFuncAttributeMaxDynamicSharedMemorySize, MID_SMEM);

  k_wpack<<<dim3(288), TPB, 0, stream>>>(w1r, w1i, w2r, w2i, wp);
  k_fwd_w<<<dim3(BH_, 12), TPB, 0, stream>>>(x, fq);
  k_mid<<<dim3(8, FW, B_), 512, MID_SMEM, stream>>>(fq, (const bf16x8*)wp, b1, b2);
  k_inv_w<<<dim3(BH_, 12), TPB, 0, stream>>>(fq, x, out);
}

// Round 5
// 333.284 us; speedup vs baseline: 1.5112x; 1.5112x over previous
//
#include <hip/hip_runtime.h>
#include <hip/hip_bf16.h>
#include <cstdio>

#define TPB 256
#define B_ 4
#define H_ 128
#define W_ 128
#define D_ 768
#define FW 65
#define BH_ 512                  // B_*H_
#define THRESH_ 0.01f
#define NEG_TWO_PI_OVER_128 (-0.04908738521234052f)

typedef short bf16x8 __attribute__((ext_vector_type(8)));
typedef float f32x4 __attribute__((ext_vector_type(4)));

// fq (in d_ws): one u32 per (point, channel) = packed (bf16 re, bf16 im)
//   u32 index = ((b*128 + h)*65 + fw)*768 + d
// Mixed-radix 128 = 4*4*4*2 DIF; slot(k) = digit-reverse:
//   s(k) = ((k&3)<<5) | (((k>>2)&3)<<3) | (((k>>4)&3)<<1) | ((k>>6)&1)

__device__ __forceinline__ unsigned pk(float lo, float hi) {
  __hip_bfloat162 h2 = __float22bfloat162_rn(make_float2(lo, hi));
  return *(unsigned*)&h2;
}
__device__ __forceinline__ float2 upk(unsigned u) {
  return __bfloat1622float2(*(__hip_bfloat162*)&u);
}
__device__ __forceinline__ int drev(int k) {
  return ((k & 3) << 5) | (((k >> 2) & 3) << 3) | (((k >> 4) & 3) << 1) | ((k >> 6) & 1);
}

// radix-4 DIF butterfly on LDS slots (used by W-axis kernels).
template <bool FWD>
__device__ __forceinline__ void bfly4(float* re, float* im, int i0, int i1, int i2, int i3,
                                      float c1, float s1, float c2, float s2, float c3, float s3) {
  const float x0r = re[i0], x0i = im[i0], x1r = re[i1], x1i = im[i1];
  const float x2r = re[i2], x2i = im[i2], x3r = re[i3], x3i = im[i3];
  const float v0r = x0r + x2r, v0i = x0i + x2i, v2r = x0r - x2r, v2i = x0i - x2i;
  const float v1r = x1r + x3r, v1i = x1i + x3i, v3r = x1r - x3r, v3i = x1i - x3i;
  float u1r, u1i, u3r, u3i;
  if (FWD) { u1r = v2r + v3i; u1i = v2i - v3r; u3r = v2r - v3i; u3i = v2i + v3r; }
  else     { u1r = v2r - v3i; u1i = v2i + v3r; u3r = v2r + v3i; u3i = v2i - v3r; }
  const float u2r = v0r - v1r, u2i = v0i - v1i;
  re[i0] = v0r + v1r; im[i0] = v0i + v1i;
  re[i1] = u1r * c1 - u1i * s1; im[i1] = u1r * s1 + u1i * c1;
  re[i2] = u2r * c2 - u2i * s2; im[i2] = u2r * s2 + u2i * c2;
  re[i3] = u3r * c3 - u3i * s3; im[i3] = u3r * s3 + u3i * c3;
}

// register-resident forward radix-4 butterfly (DIF, e^-i twiddles post-DFT4)
__device__ __forceinline__ void fbf4r(float& x0r, float& x0i, float& x1r, float& x1i,
                                      float& x2r, float& x2i, float& x3r, float& x3i,
                                      float c1, float s1, float c2, float s2, float c3, float s3) {
  const float v0r = x0r + x2r, v0i = x0i + x2i, v2r = x0r - x2r, v2i = x0i - x2i;
  const float v1r = x1r + x3r, v1i = x1i + x3i, v3r = x1r - x3r, v3i = x1i - x3i;
  const float u1r = v2r + v3i, u1i = v2i - v3r;
  const float u3r = v2r - v3i, u3i = v2i + v3r;
  const float u2r = v0r - v1r, u2i = v0i - v1i;
  x0r = v0r + v1r;            x0i = v0i + v1i;
  x1r = u1r * c1 - u1i * s1;  x1i = u1r * s1 + u1i * c1;
  x2r = u2r * c2 - u2i * s2;  x2i = u2r * s2 + u2i * c2;
  x3r = u3r * c3 - u3i * s3;  x3i = u3r * s3 + u3i * c3;
}

// register-resident inverse radix-4 butterfly (DIT: conj-twiddle inputs, e^+i DFT4)
__device__ __forceinline__ void ibf4r(float& x0r, float& x0i, float& x1r, float& x1i,
                                      float& x2r, float& x2i, float& x3r, float& x3i,
                                      float c1, float s1, float c2, float s2, float c3, float s3) {
  const float t0r = x0r, t0i = x0i;
  const float t1r = x1r * c1 + x1i * s1, t1i = x1i * c1 - x1r * s1;
  const float t2r = x2r * c2 + x2i * s2, t2i = x2i * c2 - x2r * s2;
  const float t3r = x3r * c3 + x3i * s3, t3i = x3i * c3 - x3r * s3;
  const float w0r = t0r + t2r, w0i = t0i + t2i, w2r = t0r - t2r, w2i = t0i - t2i;
  const float w1r = t1r + t3r, w1i = t1i + t3i, w3r = t1r - t3r, w3i = t1i - t3i;
  x0r = w0r + w1r; x0i = w0i + w1i;
  x1r = w2r - w3i; x1i = w2i + w3r;
  x2r = w0r - w1r; x2i = w0i - w1i;
  x3r = w2r + w3i; x3i = w2i - w3r;
}

// ===================== 256-thread [slot*32+col] helpers (W-axis kernels) ====
template <bool FWD>
__device__ __forceinline__ void run_stage(float* re, float* im, int t,
                                          int npmask, int npbits, int span, int twm,
                                          const float* twr, const float* twi) {
#pragma unroll
  for (int it = 0; it < 4; ++it) {
    const int gid = it * TPB + t;
    const int cc = gid & 31, g = gid >> 5;
    const int np = g & npmask, blk = g >> npbits;
    const int base = blk * (span << 2) + np;
    const int i0 = base * 32 + cc, i1 = (base + span) * 32 + cc;
    const int i2 = (base + 2 * span) * 32 + cc, i3 = (base + 3 * span) * 32 + cc;
    const int tb = np * twm;
    float c1 = twr[tb], s1 = twi[tb];
    float c2 = twr[2 * tb], s2 = twi[2 * tb];
    float c3 = twr[3 * tb], s3 = twi[3 * tb];
    if (!FWD) { s1 = -s1; s2 = -s2; s3 = -s3; }
    bfly4<FWD>(re, im, i0, i1, i2, i3, c1, s1, c2, s2, c3, s3);
  }
  __syncthreads();
}

__device__ __forceinline__ void run_r2(float* re, float* im, int t) {
#pragma unroll
  for (int it = 0; it < 8; ++it) {
    const int pid = it * TPB + t;
    const int cc = pid & 31, p = pid >> 5;
    const int i0 = (2 * p) * 32 + cc, i1 = i0 + 32;
    const float ar = re[i0], ai = im[i0], br = re[i1], bi = im[i1];
    re[i0] = ar + br; im[i0] = ai + bi;
    re[i1] = ar - br; im[i1] = ai - bi;
  }
  __syncthreads();
}

#define TW_INIT() do { if (t < 128) { float s_, c_; \
    __sincosf(NEG_TWO_PI_OVER_128 * (float)t, &s_, &c_); twr[t] = c_; twi[t] = s_; } } while (0)

// ---------------------------------------------------------------------------
// K0: pack complex weights into bf16 B-fragment order (block form Wc).
// ---------------------------------------------------------------------------
__global__ __launch_bounds__(TPB) void k_wpack(const float* __restrict__ w1r,
                                               const float* __restrict__ w1i,
                                               const float* __restrict__ w2r,
                                               const float* __restrict__ w2i,
                                               unsigned short* __restrict__ wp) {
  const int tid = blockIdx.x * TPB + threadIdx.x;
  if (tid >= 2 * 36864) return;
  const int L = tid / 36864, rem = tid % 36864;
  const int n = rem / 192, k = rem % 192;
  const int c = k >> 1, s = k & 1, o = n >> 1, t = n & 1;
  const float* wr = L ? w2r : w1r;
  const float* wi = L ? w2i : w1i;
  const float val = (s == 0) ? (t == 0 ? wr[o * 96 + c] : wi[o * 96 + c])
                             : (t == 0 ? -wi[o * 96 + c] : wr[o * 96 + c]);
  __hip_bfloat16 h = __float2bfloat16(val);
  const int idx = ((n * 6 + (k >> 5)) * 4 + ((k >> 3) & 3)) * 8 + (k & 7);
  wp[L * 36864 + idx] = *(unsigned short*)&h;
}

// ---------------------------------------------------------------------------
// K1: forward rFFT over W via real-pair packing. grid (512, 12). bf16 out.
// ---------------------------------------------------------------------------
__global__ __launch_bounds__(TPB) void k_fwd_w(const float* __restrict__ x,
                                               unsigned* __restrict__ fq) {
  __shared__ float re[4096], im[4096], twr[128], twi[128];
  const int t = threadIdx.x;
  const int bh = blockIdx.x;
  const int d0 = blockIdx.y << 6;
  TW_INIT();
  const float2* xp = (const float2*)(x + (size_t)bh * 98304 + d0);
#pragma unroll
  for (int it = 0; it < 16; ++it) {
    const int w = (it << 3) + (t >> 5), c = t & 31;
    const float2 v = xp[w * 384 + c];
    re[w * 32 + c] = v.x; im[w * 32 + c] = v.y;
  }
  __syncthreads();
  run_stage<true>(re, im, t, 31, 5, 32, 1, twr, twi);
  run_stage<true>(re, im, t, 7, 3, 8, 4, twr, twi);
  run_stage<true>(re, im, t, 1, 1, 2, 16, twr, twi);
  run_r2(re, im, t);
#pragma unroll
  for (int it = 0; it < 9; ++it) {
    const int idx = it * TPB + t;
    if (idx < FW * 32) {
      const int q = idx >> 5, c = idx & 31;
      const int sq = drev(q), sm = drev((128 - q) & 127);
      const float a = re[sq * 32 + c], b = im[sq * 32 + c];
      const float cr = re[sm * 32 + c], dr = -im[sm * 32 + c];
      const float hsc = 0.00390625f;  // 0.5 * (1/128)
      const float xer = (a + cr) * hsc, xei = (b + dr) * hsc;
      const float xor_ = (b - dr) * hsc, xoi = (cr - a) * hsc;
      *(uint2*)(fq + (size_t)(bh * FW + q) * 768 + d0 + 2 * c) =
          make_uint2(pk(xer, xei), pk(xor_, xoi));
    }
  }
}

// ---------------------------------------------------------------------------
// K2a: forward complex FFT over H, in-place; output digit-reversed slots.
// Two-stage register fusion: stages 1+2 (4x4 grid / thread), one LDS
// round-trip, stages 3+r2 (8 consecutive / thread). grid (4, 65, 24).
// ---------------------------------------------------------------------------
__global__ __launch_bounds__(TPB) void k_fwd_h(unsigned* __restrict__ fq) {
  __shared__ float re[4096], im[4096], twr[128], twi[128];
  const int t = threadIdx.x;
  const int b = blockIdx.x, fw = blockIdx.y, d0 = blockIdx.z << 5;
  TW_INIT();
  unsigned* fp = fq + (size_t)(b * 128 * FW + fw) * 768 + d0;
  const int c = t & 31, p = t >> 5;
  const size_t hs = (size_t)FW * 768;

  // phase 1: load h = p + 8m + 32q grid into registers
  float vr[4][4], vi[4][4];
#pragma unroll
  for (int q = 0; q < 4; ++q)
#pragma unroll
    for (int m = 0; m < 4; ++m) {
      const float2 v = upk(fp[(size_t)(p + 8 * m + 32 * q) * hs + c]);
      vr[q][m] = v.x; vi[q][m] = v.y;
    }
  __syncthreads();  // twiddle table ready
  // stage 1 (span 32): butterfly over q, np = p + 8m
#pragma unroll
  for (int m = 0; m < 4; ++m) {
    const int np = p + 8 * m;
    fbf4r(vr[0][m], vi[0][m], vr[1][m], vi[1][m], vr[2][m], vi[2][m], vr[3][m], vi[3][m],
          twr[np], twi[np], twr[2 * np], twi[2 * np], twr[3 * np], twi[3 * np]);
  }
  // stage 2 (span 8): butterfly over m, np = p
#pragma unroll
  for (int q = 0; q < 4; ++q)
    fbf4r(vr[q][0], vi[q][0], vr[q][1], vi[q][1], vr[q][2], vi[q][2], vr[q][3], vi[q][3],
          twr[4 * p], twi[4 * p], twr[8 * p], twi[8 * p], twr[12 * p], twi[12 * p]);
  // write to LDS at in-place positions
#pragma unroll
  for (int q = 0; q < 4; ++q)
#pragma unroll
    for (int m = 0; m < 4; ++m) {
      const int pos = p + 8 * m + 32 * q;
      re[pos * 32 + c] = vr[q][m]; im[pos * 32 + c] = vi[q][m];
    }
  __syncthreads();

  // phase 2: stage 3 (span 2, within 8-block) + r2, two 8-blocks per thread
#pragma unroll
  for (int half = 0; half < 2; ++half) {
    const int g = 8 * half + p;
    float wr8[8], wi8[8];
#pragma unroll
    for (int j = 0; j < 8; ++j) { wr8[j] = re[(8 * g + j) * 32 + c]; wi8[j] = im[(8 * g + j) * 32 + c]; }
    // np=0 quad {0,2,4,6}: twiddles = 1
    fbf4r(wr8[0], wi8[0], wr8[2], wi8[2], wr8[4], wi8[4], wr8[6], wi8[6],
          1.f, 0.f, 1.f, 0.f, 1.f, 0.f);
    // np=1 quad {1,3,5,7}: tw[16], tw[32], tw[48]
    fbf4r(wr8[1], wi8[1], wr8[3], wi8[3], wr8[5], wi8[5], wr8[7], wi8[7],
          twr[16], twi[16], twr[32], twi[32], twr[48], twi[48]);
    // r2 on pairs (0,1)(2,3)(4,5)(6,7)
#pragma unroll
    for (int j = 0; j < 8; j += 2) {
      const float ar = wr8[j], ai = wi8[j], br = wr8[j + 1], bi = wi8[j + 1];
      wr8[j] = ar + br; wi8[j] = ai + bi;
      wr8[j + 1] = ar - br; wi8[j + 1] = ai - bi;
    }
#pragma unroll
    for (int j = 0; j < 8; ++j)
      fp[(size_t)(8 * g + j) * hs + c] = pk(wr8[j], wi8[j]);
  }
}

// ---------------------------------------------------------------------------
// K2b: MFMA MLP, in-place on bf16 fq. M-tile 64 (24 KB LDS -> 6 WG/CU).
// ---------------------------------------------------------------------------
__global__ __launch_bounds__(TPB, 4) void k_mlp_mfma(unsigned* __restrict__ fq,
    const bf16x8* __restrict__ wpb,
    const float* __restrict__ b1, const float* __restrict__ b2) {
  __shared__ __align__(16) char lds[24576];   // 64 rows * 384 B
  const int t  = threadIdx.x;
  const int wv = t >> 6;
  const int l  = t & 63;
  const int c16 = l & 15, g = l >> 4, low3 = l & 7;
  const int n0 = wv * 48;
  const int P0 = blockIdx.x << 6;

  // stage Z tile (bf16, swizzled): 64 rows x 384 B
  const uint4* src = (const uint4*)(fq + (size_t)P0 * 96);
#pragma unroll
  for (int it = 0; it < 6; ++it) {
    const int q = it * TPB + t;                 // 1536 uint4s
    const int row = q / 24, f = q % 24;
    *(uint4*)(lds + row * 384 + ((f * 16) ^ ((row & 7) << 4))) = src[q];
  }
  __syncthreads();

  f32x4 acc[4][3];
  float bs0 = b1[n0 + c16], bs1 = b1[n0 + 16 + c16], bs2 = b1[n0 + 32 + c16];

  // ---- layer 1 ----
#pragma unroll
  for (int mt = 0; mt < 4; ++mt)
#pragma unroll
    for (int np = 0; np < 3; ++np) acc[mt][np] = (f32x4)0.f;
  for (int kk = 0; kk < 6; ++kk) {
    bf16x8 a[4];
#pragma unroll
    for (int mt = 0; mt < 4; ++mt) {
      const int row = (mt << 4) + c16;
      a[mt] = *(const bf16x8*)(lds + row * 384 + ((kk * 64 + g * 16) ^ (low3 << 4)));
    }
    bf16x8 bfr[3];
#pragma unroll
    for (int np = 0; np < 3; ++np) bfr[np] = wpb[((n0 + np * 16 + c16) * 6 + kk) * 4 + g];
#pragma unroll
    for (int mt = 0; mt < 4; ++mt)
#pragma unroll
      for (int np = 0; np < 3; ++np)
        acc[mt][np] = __builtin_amdgcn_mfma_f32_16x16x32_bf16(a[mt], bfr[np], acc[mt][np], 0, 0, 0);
  }
  __syncthreads();
  // bias + ReLU -> bf16 hidden (same swizzled layout)
#pragma unroll
  for (int mt = 0; mt < 4; ++mt)
#pragma unroll
    for (int np = 0; np < 3; ++np) {
      const int col = n0 + np * 16 + c16;
      const float bb = np == 0 ? bs0 : (np == 1 ? bs1 : bs2);
#pragma unroll
      for (int r = 0; r < 4; ++r) {
        const int row = (mt << 4) + (g << 2) + r;
        const float vv = fmaxf(acc[mt][np][r] + bb, 0.f);
        __hip_bfloat16 hb = __float2bfloat16(vv);
        *(unsigned short*)(lds + row * 384 + ((2 * col) ^ ((row & 7) << 4))) = *(unsigned short*)&hb;
      }
    }
  __syncthreads();

  // ---- layer 2 ----
  bs0 = b2[n0 + c16]; bs1 = b2[n0 + 16 + c16]; bs2 = b2[n0 + 32 + c16];
#pragma unroll
  for (int mt = 0; mt < 4; ++mt)
#pragma unroll
    for (int np = 0; np < 3; ++np) acc[mt][np] = (f32x4)0.f;
  const bf16x8* wpb2 = wpb + 4608;
  for (int kk = 0; kk < 6; ++kk) {
    bf16x8 a[4];
#pragma unroll
    for (int mt = 0; mt < 4; ++mt) {
      const int row = (mt << 4) + c16;
      a[mt] = *(const bf16x8*)(lds + row * 384 + ((kk * 64 + g * 16) ^ (low3 << 4)));
    }
    bf16x8 bfr[3];
#pragma unroll
    for (int np = 0; np < 3; ++np) bfr[np] = wpb2[((n0 + np * 16 + c16) * 6 + kk) * 4 + g];
#pragma unroll
    for (int mt = 0; mt < 4; ++mt)
#pragma unroll
      for (int np = 0; np < 3; ++np)
        acc[mt][np] = __builtin_amdgcn_mfma_f32_16x16x32_bf16(a[mt], bfr[np], acc[mt][np], 0, 0, 0);
  }
  // bias + softshrink -> bf16 global
  unsigned short* fq16 = (unsigned short*)fq;
#pragma unroll
  for (int mt = 0; mt < 4; ++mt)
#pragma unroll
    for (int np = 0; np < 3; ++np) {
      const int col = n0 + np * 16 + c16;
      const float bb = np == 0 ? bs0 : (np == 1 ? bs1 : bs2);
#pragma unroll
      for (int r = 0; r < 4; ++r) {
        const int row = (mt << 4) + (g << 2) + r;
        float vv = acc[mt][np][r] + bb;
        vv = (vv > THRESH_) ? (vv - THRESH_) : ((vv < -THRESH_) ? (vv + THRESH_) : 0.f);
        __hip_bfloat16 hb = __float2bfloat16(vv);
        fq16[(size_t)(P0 + row) * 192 + col] = *(unsigned short*)&hb;
      }
    }
}

// ---------------------------------------------------------------------------
// K2c: inverse FFT over H (DIT: digit-reversed in, natural out, e^+i),
// two-stage register fusion (mirror of k_fwd_h). In-place bf16.
// ---------------------------------------------------------------------------
__global__ __launch_bounds__(TPB) void k_inv_h(unsigned* __restrict__ fq) {
  __shared__ float re[4096], im[4096], twr[128], twi[128];
  const int t = threadIdx.x;
  const int b = blockIdx.x, fw = blockIdx.y, d0 = blockIdx.z << 5;
  TW_INIT();
  unsigned* fp = fq + (size_t)(b * 128 * FW + fw) * 768 + d0;
  const int c = t & 31, p = t >> 5;
  const size_t hs = (size_t)FW * 768;

  // phase 1: r2 + inverse stage-3 on two 8-blocks per thread
#pragma unroll
  for (int half = 0; half < 2; ++half) {
    const int g = 8 * half + p;
    float wr8[8], wi8[8];
#pragma unroll
    for (int j = 0; j < 8; ++j) {
      const float2 v = upk(fp[(size_t)(8 * g + j) * hs + c]);
      wr8[j] = v.x; wi8[j] = v.y;
    }
    if (half == 0) __syncthreads();  // twiddle table ready (once)
    // r2 on pairs
#pragma unroll
    for (int j = 0; j < 8; j += 2) {
      const float ar = wr8[j], ai = wi8[j], br = wr8[j + 1], bi = wi8[j + 1];
      wr8[j] = ar + br; wi8[j] = ai + bi;
      wr8[j + 1] = ar - br; wi8[j + 1] = ai - bi;
    }
    // inverse stage-3: np=0 quad {0,2,4,6} (tw=1), np=1 quad {1,3,5,7}
    ibf4r(wr8[0], wi8[0], wr8[2], wi8[2], wr8[4], wi8[4], wr8[6], wi8[6],
          1.f, 0.f, 1.f, 0.f, 1.f, 0.f);
    ibf4r(wr8[1], wi8[1], wr8[3], wi8[3], wr8[5], wi8[5], wr8[7], wi8[7],
          twr[16], twi[16], twr[32], twi[32], twr[48], twi[48]);
#pragma unroll
    for (int j = 0; j < 8; ++j) {
      re[(8 * g + j) * 32 + c] = wr8[j]; im[(8 * g + j) * 32 + c] = wi8[j];
    }
  }
  __syncthreads();

  // phase 2: inverse stage-2 (span 8, over m) then inverse stage-1 (span 32,
  // over q) on the 4x4 grid pos = p + 8m + 32q; store natural h.
  float vr[4][4], vi[4][4];
#pragma unroll
  for (int q = 0; q < 4; ++q)
#pragma unroll
    for (int m = 0; m < 4; ++m) {
      const int pos = p + 8 * m + 32 * q;
      vr[q][m] = re[pos * 32 + c]; vi[q][m] = im[pos * 32 + c];
    }
#pragma unroll
  for (int q = 0; q < 4; ++q)
    ibf4r(vr[q][0], vi[q][0], vr[q][1], vi[q][1], vr[q][2], vi[q][2], vr[q][3], vi[q][3],
          twr[4 * p], twi[4 * p], twr[8 * p], twi[8 * p], twr[12 * p], twi[12 * p]);
#pragma unroll
  for (int m = 0; m < 4; ++m) {
    const int np = p + 8 * m;
    ibf4r(vr[0][m], vi[0][m], vr[1][m], vi[1][m], vr[2][m], vi[2][m], vr[3][m], vi[3][m],
          twr[np], twi[np], twr[2 * np], twi[2 * np], twr[3 * np], twi[3 * np]);
  }
#pragma unroll
  for (int q = 0; q < 4; ++q)
#pragma unroll
    for (int m = 0; m < 4; ++m)
      fp[(size_t)(p + 8 * m + 32 * q) * hs + c] = pk(vr[q][m], vi[q][m]);
}

// ---------------------------------------------------------------------------
// K3: inverse rFFT over W via pair packing + skip-add. grid (512, 12).
// ---------------------------------------------------------------------------
__global__ __launch_bounds__(TPB) void k_inv_w(const unsigned* __restrict__ fq,
                                               const float* __restrict__ x,
                                               float* __restrict__ out) {
  __shared__ float re[4096], im[4096], twr[128], twi[128];
  const int t = threadIdx.x;
  const int bh = blockIdx.x;
  const int d0 = blockIdx.y << 6;
  TW_INIT();
#pragma unroll
  for (int it = 0; it < 9; ++it) {
    const int idx = it * TPB + t;
    if (idx < FW * 32) {
      const int q = idx >> 5, c = idx & 31;
      const uint2 vv = *(const uint2*)(fq + (size_t)(bh * FW + q) * 768 + d0 + 2 * c);
      const float2 e = upk(vv.x), o = upk(vv.y);
      re[q * 32 + c] = e.x - o.y; im[q * 32 + c] = e.y + o.x;
      if (q >= 1 && q <= 63) {
        re[(128 - q) * 32 + c] = e.x + o.y;
        im[(128 - q) * 32 + c] = o.x - e.y;
      }
    }
  }
  __syncthreads();
  run_stage<false>(re, im, t, 31, 5, 32, 1, twr, twi);
  run_stage<false>(re, im, t, 7, 3, 8, 4, twr, twi);
  run_stage<false>(re, im, t, 1, 1, 2, 16, twr, twi);
  run_r2(re, im, t);
  const float sc = 0.0078125f;  // 1/128
#pragma unroll
  for (int it = 0; it < 16; ++it) {
    const int w = (it << 3) + (t >> 5), c = t & 31;
    const int s = drev(w);
    const float yr = re[s * 32 + c] * sc, yi = im[s * 32 + c] * sc;
    const size_t fi = (size_t)bh * 49152 + w * 384 + (d0 >> 1) + c;
    const float2 xv = ((const float2*)x)[fi];
    ((float2*)out)[fi] = make_float2(yr + xv.x, yi + xv.y);
  }
}

// ---------------------------------------------------------------------------
extern "C" void kernel_launch(void* const* d_in, const int* in_sizes, int n_in,
                              void* d_out, int out_size, void* d_ws, size_t ws_size,
                              hipStream_t stream) {
  const float* x   = (const float*)d_in[0];
  const float* w1r = (const float*)d_in[1];
  const float* w1i = (const float*)d_in[2];
  const float* b1  = (const float*)d_in[3];
  const float* w2r = (const float*)d_in[4];
  const float* w2i = (const float*)d_in[5];
  const float* b2  = (const float*)d_in[6];
  unsigned* fq = (unsigned*)d_ws;
  float* out = (float*)d_out;

  const size_t need = (size_t)BH_ * FW * 768 * 4;  // 102,236,160 B
  if (ws_size < need) {
    fprintf(stderr, "kernel_launch: ws too small (%zu < %zu)\n", ws_size, need);
    return;
  }

  // packed bf16 weights at start of d_out (fully overwritten by k_inv_w later)
  unsigned short* wp = (unsigned short*)d_out;

  k_wpack<<<dim3(288), TPB, 0, stream>>>(w1r, w1i, w2r, w2i, wp);
  k_fwd_w<<<dim3(BH_, 12), TPB, 0, stream>>>(x, fq);
  k_fwd_h<<<dim3(B_, FW, 24), TPB, 0, stream>>>(fq);
  k_mlp_mfma<<<dim3(4160), TPB, 0, stream>>>(fq, (const bf16x8*)wp, b1, b2);
  k_inv_h<<<dim3(B_, FW, 24), TPB, 0, stream>>>(fq);
  k_inv_w<<<dim3(BH_, 12), TPB, 0, stream>>>(fq, x, out);
}

// Round 7
// 323.919 us; speedup vs baseline: 1.5549x; 1.0289x over previous
//
#include <hip/hip_runtime.h>
#include <hip/hip_bf16.h>
#include <cstdio>

#define TPB 256
#define B_ 4
#define H_ 128
#define W_ 128
#define D_ 768
#define FW 65
#define BH_ 512                  // B_*H_
#define THRESH_ 0.01f
#define NEG_TWO_PI_OVER_128 (-0.04908738521234052f)

typedef short bf16x8 __attribute__((ext_vector_type(8)));
typedef float f32x4 __attribute__((ext_vector_type(4)));

// fq (in d_ws): one u32 per (point, channel) = packed (bf16 re, bf16 im)
//   u32 index = ((b*128 + h)*65 + fw)*768 + d
// Mixed-radix 128 = 4*4*4*2 DIF; slot(k) = digit-reverse:
//   drev(k) = ((k&3)<<5) | (((k>>2)&3)<<3) | (((k>>4)&3)<<1) | ((k>>6)&1)
// NOTE: drev is NOT an involution; its inverse is drevinv below.

__device__ __forceinline__ unsigned pk(float lo, float hi) {
  __hip_bfloat162 h2 = __float22bfloat162_rn(make_float2(lo, hi));
  return *(unsigned*)&h2;
}
__device__ __forceinline__ float2 upk(unsigned u) {
  return __bfloat1622float2(*(__hip_bfloat162*)&u);
}
__device__ __forceinline__ int drev(int k) {
  return ((k & 3) << 5) | (((k >> 2) & 3) << 3) | (((k >> 4) & 3) << 1) | ((k >> 6) & 1);
}
__device__ __forceinline__ int drevinv(int s) {
  return ((s & 1) << 6) | (((s >> 1) & 3) << 4) | (((s >> 3) & 3) << 2) | ((s >> 5) & 3);
}

// register radix-4 DIF butterfly. FWD: e^-i; !FWD: e^+i (pass s = -tw_i for
// the conjugated twiddle -> bit-identical to the old LDS run_stage<false>).
template <bool FWD>
__device__ __forceinline__ void bf4reg(float& x0r, float& x0i, float& x1r, float& x1i,
                                       float& x2r, float& x2i, float& x3r, float& x3i,
                                       float c1, float s1, float c2, float s2, float c3, float s3) {
  const float v0r = x0r + x2r, v0i = x0i + x2i, v2r = x0r - x2r, v2i = x0i - x2i;
  const float v1r = x1r + x3r, v1i = x1i + x3i, v3r = x1r - x3r, v3i = x1i - x3i;
  float u1r, u1i, u3r, u3i;
  if (FWD) { u1r = v2r + v3i; u1i = v2i - v3r; u3r = v2r - v3i; u3i = v2i + v3r; }
  else     { u1r = v2r - v3i; u1i = v2i + v3r; u3r = v2r + v3i; u3i = v2i - v3r; }
  const float u2r = v0r - v1r, u2i = v0i - v1i;
  x0r = v0r + v1r;            x0i = v0i + v1i;
  x1r = u1r * c1 - u1i * s1;  x1i = u1r * s1 + u1i * c1;
  x2r = u2r * c2 - u2i * s2;  x2i = u2r * s2 + u2i * c2;
  x3r = u3r * c3 - u3i * s3;  x3i = u3r * s3 + u3i * c3;
}

// register inverse radix-4 butterfly (DIT: conj-twiddle inputs, e^+i DFT4)
__device__ __forceinline__ void ibf4r(float& x0r, float& x0i, float& x1r, float& x1i,
                                      float& x2r, float& x2i, float& x3r, float& x3i,
                                      float c1, float s1, float c2, float s2, float c3, float s3) {
  const float t0r = x0r, t0i = x0i;
  const float t1r = x1r * c1 + x1i * s1, t1i = x1i * c1 - x1r * s1;
  const float t2r = x2r * c2 + x2i * s2, t2i = x2i * c2 - x2r * s2;
  const float t3r = x3r * c3 + x3i * s3, t3i = x3i * c3 - x3r * s3;
  const float w0r = t0r + t2r, w0i = t0i + t2i, w2r = t0r - t2r, w2i = t0i - t2i;
  const float w1r = t1r + t3r, w1i = t1i + t3i, w3r = t1r - t3r, w3i = t1i - t3i;
  x0r = w0r + w1r; x0i = w0i + w1i;
  x1r = w2r - w3i; x1i = w2i + w3r;
  x2r = w0r - w1r; x2i = w0i - w1i;
  x3r = w2r + w3i; x3i = w2i - w3r;
}

#define TW_INIT() do { if (t < 128) { float s_, c_; \
    __sincosf(NEG_TWO_PI_OVER_128 * (float)t, &s_, &c_); twr[t] = c_; twi[t] = s_; } } while (0)

// ---------------------------------------------------------------------------
// K0: pack complex weights into bf16 B-fragment order (block form Wc).
// ---------------------------------------------------------------------------
__global__ __launch_bounds__(TPB) void k_wpack(const float* __restrict__ w1r,
                                               const float* __restrict__ w1i,
                                               const float* __restrict__ w2r,
                                               const float* __restrict__ w2i,
                                               unsigned short* __restrict__ wp) {
  const int tid = blockIdx.x * TPB + threadIdx.x;
  if (tid >= 2 * 36864) return;
  const int L = tid / 36864, rem = tid % 36864;
  const int n = rem / 192, k = rem % 192;
  const int c = k >> 1, s = k & 1, o = n >> 1, t = n & 1;
  const float* wr = L ? w2r : w1r;
  const float* wi = L ? w2i : w1i;
  const float val = (s == 0) ? (t == 0 ? wr[o * 96 + c] : wi[o * 96 + c])
                             : (t == 0 ? -wi[o * 96 + c] : wr[o * 96 + c]);
  __hip_bfloat16 h = __float2bfloat16(val);
  const int idx = ((n * 6 + (k >> 5)) * 4 + ((k >> 3) & 3)) * 8 + (k & 7);
  wp[L * 36864 + idx] = *(unsigned short*)&h;
}

// ---------------------------------------------------------------------------
// K1: forward rFFT over W via real-pair packing, two-phase register fusion.
// grid (512, 12). Writes bf16 fq bins 0..64.
// ---------------------------------------------------------------------------
__global__ __launch_bounds__(TPB) void k_fwd_w(const float* __restrict__ x,
                                               unsigned* __restrict__ fq) {
  __shared__ float re[4096], im[4096], twr[128], twi[128];
  const int t = threadIdx.x;
  const int bh = blockIdx.x;
  const int d0 = blockIdx.y << 6;
  TW_INIT();
  const int c = t & 31, p = t >> 5;
  const float2* xp = (const float2*)(x + (size_t)bh * 98304 + d0);

  // phase 1: load w = p+8m+32q grid into registers
  float vr[4][4], vi[4][4];
#pragma unroll
  for (int q = 0; q < 4; ++q)
#pragma unroll
    for (int m = 0; m < 4; ++m) {
      const float2 v = xp[(p + 8 * m + 32 * q) * 384 + c];
      vr[q][m] = v.x; vi[q][m] = v.y;
    }
  __syncthreads();  // twiddle table ready
  // stage 1 (span 32): over q, np = p+8m
#pragma unroll
  for (int m = 0; m < 4; ++m) {
    const int np = p + 8 * m;
    bf4reg<true>(vr[0][m], vi[0][m], vr[1][m], vi[1][m], vr[2][m], vi[2][m], vr[3][m], vi[3][m],
                 twr[np], twi[np], twr[2 * np], twi[2 * np], twr[3 * np], twi[3 * np]);
  }
  // stage 2 (span 8): over m, np = p
#pragma unroll
  for (int q = 0; q < 4; ++q)
    bf4reg<true>(vr[q][0], vi[q][0], vr[q][1], vi[q][1], vr[q][2], vi[q][2], vr[q][3], vi[q][3],
                 twr[4 * p], twi[4 * p], twr[8 * p], twi[8 * p], twr[12 * p], twi[12 * p]);
#pragma unroll
  for (int q = 0; q < 4; ++q)
#pragma unroll
    for (int m = 0; m < 4; ++m) {
      const int pos = p + 8 * m + 32 * q;
      re[pos * 32 + c] = vr[q][m]; im[pos * 32 + c] = vi[q][m];
    }
  __syncthreads();

  // phase 2: stage 3 (span 2) + r2 on two 8-blocks per thread
#pragma unroll
  for (int half = 0; half < 2; ++half) {
    const int g = 8 * half + p;
    float wr8[8], wi8[8];
#pragma unroll
    for (int j = 0; j < 8; ++j) { wr8[j] = re[(8 * g + j) * 32 + c]; wi8[j] = im[(8 * g + j) * 32 + c]; }
    bf4reg<true>(wr8[0], wi8[0], wr8[2], wi8[2], wr8[4], wi8[4], wr8[6], wi8[6],
                 1.f, 0.f, 1.f, 0.f, 1.f, 0.f);
    bf4reg<true>(wr8[1], wi8[1], wr8[3], wi8[3], wr8[5], wi8[5], wr8[7], wi8[7],
                 twr[16], twi[16], twr[32], twi[32], twr[48], twi[48]);
#pragma unroll
    for (int j = 0; j < 8; j += 2) {
      const float ar = wr8[j], ai = wi8[j], br = wr8[j + 1], bi = wi8[j + 1];
      wr8[j] = ar + br; wi8[j] = ai + bi;
      wr8[j + 1] = ar - br; wi8[j + 1] = ai - bi;
    }
#pragma unroll
    for (int j = 0; j < 8; ++j) {
      re[(8 * g + j) * 32 + c] = wr8[j]; im[(8 * g + j) * 32 + c] = wi8[j];
    }
  }
  __syncthreads();

  // epilogue: unpack real-pair spectrum + ortho scale, write bins 0..64
#pragma unroll
  for (int it = 0; it < 9; ++it) {
    const int idx = it * TPB + t;
    if (idx < FW * 32) {
      const int q = idx >> 5, cc = idx & 31;
      const int sq = drev(q), smm = drev((128 - q) & 127);
      const float a = re[sq * 32 + cc], b = im[sq * 32 + cc];
      const float cr = re[smm * 32 + cc], dr = -im[smm * 32 + cc];
      const float hsc = 0.00390625f;  // 0.5 * (1/128)
      const float xer = (a + cr) * hsc, xei = (b + dr) * hsc;
      const float xor_ = (b - dr) * hsc, xoi = (cr - a) * hsc;
      *(uint2*)(fq + (size_t)(bh * FW + q) * 768 + d0 + 2 * cc) =
          make_uint2(pk(xer, xei), pk(xor_, xoi));
    }
  }
}

// ---------------------------------------------------------------------------
// K2a: forward complex FFT over H, in-place; output digit-reversed slots.
// Two-stage register fusion. grid (4, 65, 24).
// ---------------------------------------------------------------------------
__global__ __launch_bounds__(TPB) void k_fwd_h(unsigned* __restrict__ fq) {
  __shared__ float re[4096], im[4096], twr[128], twi[128];
  const int t = threadIdx.x;
  const int b = blockIdx.x, fw = blockIdx.y, d0 = blockIdx.z << 5;
  TW_INIT();
  unsigned* fp = fq + (size_t)(b * 128 * FW + fw) * 768 + d0;
  const int c = t & 31, p = t >> 5;
  const size_t hs = (size_t)FW * 768;

  float vr[4][4], vi[4][4];
#pragma unroll
  for (int q = 0; q < 4; ++q)
#pragma unroll
    for (int m = 0; m < 4; ++m) {
      const float2 v = upk(fp[(size_t)(p + 8 * m + 32 * q) * hs + c]);
      vr[q][m] = v.x; vi[q][m] = v.y;
    }
  __syncthreads();  // twiddle table ready
#pragma unroll
  for (int m = 0; m < 4; ++m) {
    const int np = p + 8 * m;
    bf4reg<true>(vr[0][m], vi[0][m], vr[1][m], vi[1][m], vr[2][m], vi[2][m], vr[3][m], vi[3][m],
                 twr[np], twi[np], twr[2 * np], twi[2 * np], twr[3 * np], twi[3 * np]);
  }
#pragma unroll
  for (int q = 0; q < 4; ++q)
    bf4reg<true>(vr[q][0], vi[q][0], vr[q][1], vi[q][1], vr[q][2], vi[q][2], vr[q][3], vi[q][3],
                 twr[4 * p], twi[4 * p], twr[8 * p], twi[8 * p], twr[12 * p], twi[12 * p]);
#pragma unroll
  for (int q = 0; q < 4; ++q)
#pragma unroll
    for (int m = 0; m < 4; ++m) {
      const int pos = p + 8 * m + 32 * q;
      re[pos * 32 + c] = vr[q][m]; im[pos * 32 + c] = vi[q][m];
    }
  __syncthreads();

#pragma unroll
  for (int half = 0; half < 2; ++half) {
    const int g = 8 * half + p;
    float wr8[8], wi8[8];
#pragma unroll
    for (int j = 0; j < 8; ++j) { wr8[j] = re[(8 * g + j) * 32 + c]; wi8[j] = im[(8 * g + j) * 32 + c]; }
    bf4reg<true>(wr8[0], wi8[0], wr8[2], wi8[2], wr8[4], wi8[4], wr8[6], wi8[6],
                 1.f, 0.f, 1.f, 0.f, 1.f, 0.f);
    bf4reg<true>(wr8[1], wi8[1], wr8[3], wi8[3], wr8[5], wi8[5], wr8[7], wi8[7],
                 twr[16], twi[16], twr[32], twi[32], twr[48], twi[48]);
#pragma unroll
    for (int j = 0; j < 8; j += 2) {
      const float ar = wr8[j], ai = wi8[j], br = wr8[j + 1], bi = wi8[j + 1];
      wr8[j] = ar + br; wi8[j] = ai + bi;
      wr8[j + 1] = ar - br; wi8[j + 1] = ai - bi;
    }
#pragma unroll
    for (int j = 0; j < 8; ++j)
      fp[(size_t)(8 * g + j) * hs + c] = pk(wr8[j], wi8[j]);
  }
}

// ---------------------------------------------------------------------------
// K2b: MFMA MLP, in-place on bf16 fq. M-tile 64 (24 KB LDS).
// ---------------------------------------------------------------------------
__global__ __launch_bounds__(TPB, 4) void k_mlp_mfma(unsigned* __restrict__ fq,
    const bf16x8* __restrict__ wpb,
    const float* __restrict__ b1, const float* __restrict__ b2) {
  __shared__ __align__(16) char lds[24576];   // 64 rows * 384 B
  const int t  = threadIdx.x;
  const int wv = t >> 6;
  const int l  = t & 63;
  const int c16 = l & 15, g = l >> 4, low3 = l & 7;
  const int n0 = wv * 48;
  const int P0 = blockIdx.x << 6;

  const uint4* src = (const uint4*)(fq + (size_t)P0 * 96);
#pragma unroll
  for (int it = 0; it < 6; ++it) {
    const int q = it * TPB + t;                 // 1536 uint4s
    const int row = q / 24, f = q % 24;
    *(uint4*)(lds + row * 384 + ((f * 16) ^ ((row & 7) << 4))) = src[q];
  }
  __syncthreads();

  f32x4 acc[4][3];
  float bs0 = b1[n0 + c16], bs1 = b1[n0 + 16 + c16], bs2 = b1[n0 + 32 + c16];

#pragma unroll
  for (int mt = 0; mt < 4; ++mt)
#pragma unroll
    for (int np = 0; np < 3; ++np) acc[mt][np] = (f32x4)0.f;
  for (int kk = 0; kk < 6; ++kk) {
    bf16x8 a[4];
#pragma unroll
    for (int mt = 0; mt < 4; ++mt) {
      const int row = (mt << 4) + c16;
      a[mt] = *(const bf16x8*)(lds + row * 384 + ((kk * 64 + g * 16) ^ (low3 << 4)));
    }
    bf16x8 bfr[3];
#pragma unroll
    for (int np = 0; np < 3; ++np) bfr[np] = wpb[((n0 + np * 16 + c16) * 6 + kk) * 4 + g];
#pragma unroll
    for (int mt = 0; mt < 4; ++mt)
#pragma unroll
      for (int np = 0; np < 3; ++np)
        acc[mt][np] = __builtin_amdgcn_mfma_f32_16x16x32_bf16(a[mt], bfr[np], acc[mt][np], 0, 0, 0);
  }
  __syncthreads();
#pragma unroll
  for (int mt = 0; mt < 4; ++mt)
#pragma unroll
    for (int np = 0; np < 3; ++np) {
      const int col = n0 + np * 16 + c16;
      const float bb = np == 0 ? bs0 : (np == 1 ? bs1 : bs2);
#pragma unroll
      for (int r = 0; r < 4; ++r) {
        const int row = (mt << 4) + (g << 2) + r;
        const float vv = fmaxf(acc[mt][np][r] + bb, 0.f);
        __hip_bfloat16 hb = __float2bfloat16(vv);
        *(unsigned short*)(lds + row * 384 + ((2 * col) ^ ((row & 7) << 4))) = *(unsigned short*)&hb;
      }
    }
  __syncthreads();

  bs0 = b2[n0 + c16]; bs1 = b2[n0 + 16 + c16]; bs2 = b2[n0 + 32 + c16];
#pragma unroll
  for (int mt = 0; mt < 4; ++mt)
#pragma unroll
    for (int np = 0; np < 3; ++np) acc[mt][np] = (f32x4)0.f;
  const bf16x8* wpb2 = wpb + 4608;
  for (int kk = 0; kk < 6; ++kk) {
    bf16x8 a[4];
#pragma unroll
    for (int mt = 0; mt < 4; ++mt) {
      const int row = (mt << 4) + c16;
      a[mt] = *(const bf16x8*)(lds + row * 384 + ((kk * 64 + g * 16) ^ (low3 << 4)));
    }
    bf16x8 bfr[3];
#pragma unroll
    for (int np = 0; np < 3; ++np) bfr[np] = wpb2[((n0 + np * 16 + c16) * 6 + kk) * 4 + g];
#pragma unroll
    for (int mt = 0; mt < 4; ++mt)
#pragma unroll
      for (int np = 0; np < 3; ++np)
        acc[mt][np] = __builtin_amdgcn_mfma_f32_16x16x32_bf16(a[mt], bfr[np], acc[mt][np], 0, 0, 0);
  }
  unsigned short* fq16 = (unsigned short*)fq;
#pragma unroll
  for (int mt = 0; mt < 4; ++mt)
#pragma unroll
    for (int np = 0; np < 3; ++np) {
      const int col = n0 + np * 16 + c16;
      const float bb = np == 0 ? bs0 : (np == 1 ? bs1 : bs2);
#pragma unroll
      for (int r = 0; r < 4; ++r) {
        const int row = (mt << 4) + (g << 2) + r;
        float vv = acc[mt][np][r] + bb;
        vv = (vv > THRESH_) ? (vv - THRESH_) : ((vv < -THRESH_) ? (vv + THRESH_) : 0.f);
        __hip_bfloat16 hb = __float2bfloat16(vv);
        fq16[(size_t)(P0 + row) * 192 + col] = *(unsigned short*)&hb;
      }
    }
}

// ---------------------------------------------------------------------------
// K2c: inverse FFT over H (DIT, digit-reversed in, natural out, e^+i),
// two-stage register fusion. In-place bf16. grid (4, 65, 24).
// ---------------------------------------------------------------------------
__global__ __launch_bounds__(TPB) void k_inv_h(unsigned* __restrict__ fq) {
  __shared__ float re[4096], im[4096], twr[128], twi[128];
  const int t = threadIdx.x;
  const int b = blockIdx.x, fw = blockIdx.y, d0 = blockIdx.z << 5;
  TW_INIT();
  unsigned* fp = fq + (size_t)(b * 128 * FW + fw) * 768 + d0;
  const int c = t & 31, p = t >> 5;
  const size_t hs = (size_t)FW * 768;

#pragma unroll
  for (int half = 0; half < 2; ++half) {
    const int g = 8 * half + p;
    float wr8[8], wi8[8];
#pragma unroll
    for (int j = 0; j < 8; ++j) {
      const float2 v = upk(fp[(size_t)(8 * g + j) * hs + c]);
      wr8[j] = v.x; wi8[j] = v.y;
    }
    if (half == 0) __syncthreads();  // twiddle table ready (once)
#pragma unroll
    for (int j = 0; j < 8; j += 2) {
      const float ar = wr8[j], ai = wi8[j], br = wr8[j + 1], bi = wi8[j + 1];
      wr8[j] = ar + br; wi8[j] = ai + bi;
      wr8[j + 1] = ar - br; wi8[j + 1] = ai - bi;
    }
    ibf4r(wr8[0], wi8[0], wr8[2], wi8[2], wr8[4], wi8[4], wr8[6], wi8[6],
          1.f, 0.f, 1.f, 0.f, 1.f, 0.f);
    ibf4r(wr8[1], wi8[1], wr8[3], wi8[3], wr8[5], wi8[5], wr8[7], wi8[7],
          twr[16], twi[16], twr[32], twi[32], twr[48], twi[48]);
#pragma unroll
    for (int j = 0; j < 8; ++j) {
      re[(8 * g + j) * 32 + c] = wr8[j]; im[(8 * g + j) * 32 + c] = wi8[j];
    }
  }
  __syncthreads();

  float vr[4][4], vi[4][4];
#pragma unroll
  for (int q = 0; q < 4; ++q)
#pragma unroll
    for (int m = 0; m < 4; ++m) {
      const int pos = p + 8 * m + 32 * q;
      vr[q][m] = re[pos * 32 + c]; vi[q][m] = im[pos * 32 + c];
    }
#pragma unroll
  for (int q = 0; q < 4; ++q)
    ibf4r(vr[q][0], vi[q][0], vr[q][1], vi[q][1], vr[q][2], vi[q][2], vr[q][3], vi[q][3],
          twr[4 * p], twi[4 * p], twr[8 * p], twi[8 * p], twr[12 * p], twi[12 * p]);
#pragma unroll
  for (int m = 0; m < 4; ++m) {
    const int np = p + 8 * m;
    ibf4r(vr[0][m], vi[0][m], vr[1][m], vi[1][m], vr[2][m], vi[2][m], vr[3][m], vi[3][m],
          twr[np], twi[np], twr[2 * np], twi[2 * np], twr[3 * np], twi[3 * np]);
  }
#pragma unroll
  for (int q = 0; q < 4; ++q)
#pragma unroll
    for (int m = 0; m < 4; ++m)
      fp[(size_t)(p + 8 * m + 32 * q) * hs + c] = pk(vr[q][m], vi[q][m]);
}

// ---------------------------------------------------------------------------
// K3: inverse rFFT over W, two-phase register fusion + direct global store
// with skip-add. Sample for slot s is drevinv(s). grid (512, 12).
// ---------------------------------------------------------------------------
__global__ __launch_bounds__(TPB) void k_inv_w(const unsigned* __restrict__ fq,
                                               const float* __restrict__ x,
                                               float* __restrict__ out) {
  __shared__ float re[4096], im[4096], twr[128], twi[128];
  const int t = threadIdx.x;
  const int bh = blockIdx.x;
  const int d0 = blockIdx.y << 6;
  TW_INIT();
  const int c = t & 31, p = t >> 5;
  const float sc = 0.0078125f;  // 1/128 (folded into the Hermitian build)

  // build full 128-bin spectrum (Z = Ye + i*Yo), scaled
#pragma unroll
  for (int it = 0; it < 9; ++it) {
    const int idx = it * TPB + t;
    if (idx < FW * 32) {
      const int q = idx >> 5, cc = idx & 31;
      const uint2 vv = *(const uint2*)(fq + (size_t)(bh * FW + q) * 768 + d0 + 2 * cc);
      const float2 e = upk(vv.x), o = upk(vv.y);
      re[q * 32 + cc] = (e.x - o.y) * sc; im[q * 32 + cc] = (e.y + o.x) * sc;
      if (q >= 1 && q <= 63) {
        re[(128 - q) * 32 + cc] = (e.x + o.y) * sc;
        im[(128 - q) * 32 + cc] = (o.x - e.y) * sc;
      }
    }
  }
  __syncthreads();  // build visible + twiddles ready

  // stages 1+2 in registers (inverse DIF: conj twiddles)
  float vr[4][4], vi[4][4];
#pragma unroll
  for (int q = 0; q < 4; ++q)
#pragma unroll
    for (int m = 0; m < 4; ++m) {
      const int pos = p + 8 * m + 32 * q;
      vr[q][m] = re[pos * 32 + c]; vi[q][m] = im[pos * 32 + c];
    }
#pragma unroll
  for (int m = 0; m < 4; ++m) {
    const int np = p + 8 * m;
    bf4reg<false>(vr[0][m], vi[0][m], vr[1][m], vi[1][m], vr[2][m], vi[2][m], vr[3][m], vi[3][m],
                  twr[np], -twi[np], twr[2 * np], -twi[2 * np], twr[3 * np], -twi[3 * np]);
  }
#pragma unroll
  for (int q = 0; q < 4; ++q)
    bf4reg<false>(vr[q][0], vi[q][0], vr[q][1], vi[q][1], vr[q][2], vi[q][2], vr[q][3], vi[q][3],
                  twr[4 * p], -twi[4 * p], twr[8 * p], -twi[8 * p], twr[12 * p], -twi[12 * p]);
#pragma unroll
  for (int q = 0; q < 4; ++q)
#pragma unroll
    for (int m = 0; m < 4; ++m) {
      const int pos = p + 8 * m + 32 * q;
      re[pos * 32 + c] = vr[q][m]; im[pos * 32 + c] = vi[q][m];
    }
  __syncthreads();

  // stage 3 + r2 in registers, then direct store (slot s -> sample drevinv(s))
  const float2* xv = (const float2*)x;
  float2* ov = (float2*)out;
#pragma unroll
  for (int half = 0; half < 2; ++half) {
    const int g = 8 * half + p;
    float wr8[8], wi8[8];
#pragma unroll
    for (int j = 0; j < 8; ++j) { wr8[j] = re[(8 * g + j) * 32 + c]; wi8[j] = im[(8 * g + j) * 32 + c]; }
    bf4reg<false>(wr8[0], wi8[0], wr8[2], wi8[2], wr8[4], wi8[4], wr8[6], wi8[6],
                  1.f, 0.f, 1.f, 0.f, 1.f, 0.f);
    bf4reg<false>(wr8[1], wi8[1], wr8[3], wi8[3], wr8[5], wi8[5], wr8[7], wi8[7],
                  twr[16], -twi[16], twr[32], -twi[32], twr[48], -twi[48]);
#pragma unroll
    for (int j = 0; j < 8; j += 2) {
      const float ar = wr8[j], ai = wi8[j], br = wr8[j + 1], bi = wi8[j + 1];
      wr8[j] = ar + br; wi8[j] = ai + bi;
      wr8[j + 1] = ar - br; wi8[j + 1] = ai - bi;
    }
#pragma unroll
    for (int j = 0; j < 8; ++j) {
      const int w = drevinv(8 * g + j);
      const size_t fi = (size_t)bh * 49152 + w * 384 + (d0 >> 1) + c;
      const float2 s = xv[fi];
      ov[fi] = make_float2(wr8[j] + s.x, wi8[j] + s.y);
    }
  }
}

// ---------------------------------------------------------------------------
extern "C" void kernel_launch(void* const* d_in, const int* in_sizes, int n_in,
                              void* d_out, int out_size, void* d_ws, size_t ws_size,
                              hipStream_t stream) {
  const float* x   = (const float*)d_in[0];
  const float* w1r = (const float*)d_in[1];
  const float* w1i = (const float*)d_in[2];
  const float* b1  = (const float*)d_in[3];
  const float* w2r = (const float*)d_in[4];
  const float* w2i = (const float*)d_in[5];
  const float* b2  = (const float*)d_in[6];
  unsigned* fq = (unsigned*)d_ws;
  float* out = (float*)d_out;

  const size_t need = (size_t)BH_ * FW * 768 * 4;  // 102,236,160 B
  if (ws_size < need) {
    fprintf(stderr, "kernel_launch: ws too small (%zu < %zu)\n", ws_size, need);
    return;
  }

  // packed bf16 weights at start of d_out (fully overwritten by k_inv_w later)
  unsigned short* wp = (unsigned short*)d_out;

  k_wpack<<<dim3(288), TPB, 0, stream>>>(w1r, w1i, w2r, w2i, wp);
  k_fwd_w<<<dim3(BH_, 12), TPB, 0, stream>>>(x, fq);
  k_fwd_h<<<dim3(B_, FW, 24), TPB, 0, stream>>>(fq);
  k_mlp_mfma<<<dim3(4160), TPB, 0, stream>>>(fq, (const bf16x8*)wp, b1, b2);
  k_inv_h<<<dim3(B_, FW, 24), TPB, 0, stream>>>(fq);
  k_inv_w<<<dim3(BH_, 12), TPB, 0, stream>>>(fq, x, out);
}